// Round 17
// baseline (103.384 us; speedup 1.0000x reference)
//
#include <hip/hip_runtime.h>
#include <hip/hip_fp16.h>
#include <hip/hip_cooperative_groups.h>

namespace cg = cooperative_groups;

// Problem constants (fixed by setup_inputs):
//   x: (64,1,8,8) f32; KH=KW=5 -> oh=ow=4; rows n = b*16 + s, N = 1024
//   feat[n, i*5+j] = x[b*64 + (oy+i)*8 + (ox+j)], s = oy*4+ox
//   idx0:(128,36,6) in [0,25), lut0:(128,36,64)
//   idx1:(128, 6,6) in [0,36), lut1:(128, 6,64)
//   idx2:(128, 1,6) in [0, 6), lut2:(128, 1,64)
//   out[b,t,oy,ox] = b*2048 + t*16 + s
#define T_TREES 128
#define M0 36
#define M1 6
#define NNODES 43
#define XPAD 67   // odd LDS image stride -> gather banks sweep residues (~2-way, free)
#define SLUT_ELEMS (T_TREES * NNODES * 64)   // 1.41 MB
#define TREE_SL (NNODES * 64)                // 2752

typedef float v2f __attribute__((ext_vector_type(2)));

__device__ __forceinline__ float sigmoidf(float v) {
    return 1.f / (1.f + __expf(-v));
}

// Pair-weight, FMA-lean: {(1-a)(1-b),(1-a)b,a(1-b),ab} per 2-row lane.
__device__ __forceinline__ void pair_w(v2f a, v2f b, v2f w[4]) {
    v2f ab = a * b;
    w[3] = ab;
    w[2] = a - ab;
    w[1] = b - ab;
    w[0] = (1.f - a) - w[1];
}

// Trilinear contraction over a row-pair; P compile-time indexed (regs).
__device__ __forceinline__ v2f lut_node_v2(const float* __restrict__ P,
                                           v2f a, v2f b, v2f c,
                                           v2f d, v2f e, v2f f) {
    v2f wa[4], wb[4], wc[4];
    pair_w(a, b, wa);
    pair_w(c, d, wb);
    pair_w(e, f, wc);
    v2f acc = {0.f, 0.f};
#pragma unroll
    for (int p = 0; p < 4; ++p) {
        v2f tp = {0.f, 0.f};
#pragma unroll
        for (int q = 0; q < 4; ++q) {
            const float* Pq = P + p * 16 + q * 4;
            v2f tq = Pq[0] * wc[0] + Pq[1] * wc[1] + Pq[2] * wc[2] + Pq[3] * wc[3];
            tp += tq * wb[q];
        }
        acc += tp * wa[p];
    }
    return acc;
}

// batch-hoist one node's 64 sigmoided LUT values from global (wave-uniform
// address -> scalar/L2 path, off the LDS pipe; one wait, then load-free FMAs).
__device__ __forceinline__ void hoist_P(const float* __restrict__ src, float P[64]) {
#pragma unroll
    for (int i = 0; i < 16; ++i) {
        float4 v = reinterpret_cast<const float4*>(src)[i];
        P[4 * i] = v.x; P[4 * i + 1] = v.y; P[4 * i + 2] = v.z; P[4 * i + 3] = v.w;
    }
}

// shared body: layers 0-2 for (tree t, eighth e), slut pre-sigmoided
__device__ __forceinline__ void run_tree_eighth(
    int t, int e, int tid,
    const float* __restrict__ xs,            // staged 8 images, XPAD stride
    const int* __restrict__ idx0, const int* __restrict__ idx1,
    const int* __restrict__ idx2, const float* __restrict__ slut,
    __half2* __restrict__ h0s, float* __restrict__ h1s,
    float* __restrict__ out) {
    const int w = __builtin_amdgcn_readfirstlane(tid >> 6);  // uniform wave id
    const int ln = tid & 63;
    const float* __restrict__ slt = slut + t * TREE_SL;

    // ---- layer 0: wave w -> nodes 9w..9w+8, one 64-pair iter each ----
#pragma unroll 1
    for (int k = 0; k < 9; ++k) {
        const int m = w * 9 + k;
        float P[64];
        hoist_P(slt + m * 64, P);
        const int* id = idx0 + (t * M0 + m) * 6;   // wave-uniform -> scalar
        int di[6];
#pragma unroll
        for (int j = 0; j < 6; ++j) {
            int kk = id[j];
            int ii = (kk * 13) >> 6;      // kk/5 for kk in [0,25)
            di[j] = kk - 5 * ii + ii * 8; // i*8 + j window offset
        }
        int b = ln >> 3;                  // local image [0,8)
        int s = (ln & 7) * 2;             // even position
        int xb = b * XPAD + (s >> 2) * 8 + (s & 3);
        v2f g[6];
#pragma unroll
        for (int j = 0; j < 6; ++j) {
            int a0 = xb + di[j];
            g[j].x = xs[a0];              // fuses -> ds_read2_b32
            g[j].y = xs[a0 + 1];
        }
        v2f r = lut_node_v2(P, g[0], g[1], g[2], g[3], g[4], g[5]);
        h0s[m * 64 + ln] = __floats2half2_rn(r.x, r.y);
    }
    __syncthreads();

    // ---- layer 1: wave0: nodes 0,4; wave1: 1,5; wave2: 2; wave3: 3 ----
#pragma unroll 1
    for (int m1 = w; m1 < M1; m1 += 4) {
        float P[64];
        hoist_P(slt + (M0 + m1) * 64, P);
        const int* id = idx1 + (t * M1 + m1) * 6;
        v2f g[6];
#pragma unroll
        for (int j = 0; j < 6; ++j) {
            float2 f = __half22float2(h0s[id[j] * 64 + ln]);
            g[j].x = f.x; g[j].y = f.y;
        }
        v2f r = lut_node_v2(P, g[0], g[1], g[2], g[3], g[4], g[5]);
        *reinterpret_cast<v2f*>(h1s + m1 * 128 + 2 * ln) = r;
    }
    __syncthreads();

    // ---- layer 2: wave 0, one pair per lane ----
    if (tid < 64) {
        float P[64];
        hoist_P(slt + (M0 + M1) * 64, P);
        const int* id = idx2 + t * 6;
        int rl = 2 * tid;
        v2f g[6];
#pragma unroll
        for (int j = 0; j < 6; ++j)
            g[j] = *reinterpret_cast<const v2f*>(h1s + id[j] * 128 + rl);
        v2f o = lut_node_v2(P, g[0], g[1], g[2], g[3], g[4], g[5]);
        int row = e * 128 + rl;
        int b = row >> 4, s = row & 15;
        *reinterpret_cast<v2f*>(out + b * (T_TREES * 16) + t * 16 + s) = o;
    }
}

// ===== cooperative single-launch: sig phase + grid.sync + fused body =====
// Phase A: block (e,t) computes slice e of TREE t's sigmoided LUT (344 elems)
// -> writers and readers of slut[t] are the same 8 blocks, all on XCD t%8
// (bx mod 8 == t mod 8), so the handoff is XCD-local L2. x staged during
// phase A (overlaps). grid.sync() then R16's proven fused body (global
// P-hoist off the LDS pipe). Saves the ~3.5us separate prepass dispatch.
// Residency for coop: 1024 blocks = 4/CU (9.8 KB LDS, <=128 VGPR via (256,4)).
__global__ __launch_bounds__(256, 4) void coop_kernel(
    const float* __restrict__ x,
    const int* __restrict__ idx0, const float* __restrict__ lut0,
    const int* __restrict__ idx1, const float* __restrict__ lut1,
    const int* __restrict__ idx2, const float* __restrict__ lut2,
    float* __restrict__ slut, float* __restrict__ out) {
    __shared__ float xs[8 * XPAD];                // 2144 B
    __shared__ __half2 h0s[M0 * 64];              // 4608 B
    __shared__ __align__(8) float h1s[M1 * 128];  // 3072 B  => 9824 B

    const int tid = threadIdx.x;
    const int bx = blockIdx.x;            // bx = e*128 + t
    const int t = bx & 127;
    const int e = bx >> 7;

    // ---- phase A: stage x eighth + compute slice e of tree t's slut ----
    const float* __restrict__ xq = x + e * 512;
    for (int i = tid; i < 512; i += 256)
        xs[(i >> 6) * XPAD + (i & 63)] = xq[i];
#pragma unroll
    for (int i = tid; i < 344; i += 256) {
        int local = e * 344 + i;          // [0, 2752)
        int node = local >> 6;
        int j = local & 63;
        float v;
        if (node < M0)            v = lut0[(t * M0 + node) * 64 + j];
        else if (node < M0 + M1)  v = lut1[(t * M1 + (node - M0)) * 64 + j];
        else                      v = lut2[t * 64 + j];
        slut[t * TREE_SL + local] = sigmoidf(v);
    }

    cg::this_grid().sync();

    // ---- phase B: fused 3-layer body (R16, proven ~20.7us standalone) ----
    run_tree_eighth(t, e, tid, xs, idx0, idx1, idx2, slut, h0s, h1s, out);
}

// ===== non-coop fallback pieces (R16 two-dispatch path, proven pass) =====
__global__ __launch_bounds__(256) void sig_kernel(
    const float* __restrict__ lut0, const float* __restrict__ lut1,
    const float* __restrict__ lut2, float* __restrict__ slut) {
    int i4 = blockIdx.x * 256 + threadIdx.x;
    int j4 = i4 & 15;
    int tn = i4 >> 4;
    int t = tn / NNODES;
    int node = tn - t * NNODES;
    const float4* src;
    if (node < M0)            src = (const float4*)lut0 + (t * M0 + node) * 16 + j4;
    else if (node < M0 + M1)  src = (const float4*)lut1 + (t * M1 + (node - M0)) * 16 + j4;
    else                      src = (const float4*)lut2 + t * 16 + j4;
    float4 v = *src;
    float4 r;
    r.x = sigmoidf(v.x); r.y = sigmoidf(v.y);
    r.z = sigmoidf(v.z); r.w = sigmoidf(v.w);
    reinterpret_cast<float4*>(slut)[i4] = r;
}

__global__ __launch_bounds__(256, 4) void fused_kernel(
    const float* __restrict__ x,
    const int* __restrict__ idx0, const int* __restrict__ idx1,
    const int* __restrict__ idx2, const float* __restrict__ slut,
    float* __restrict__ out) {
    __shared__ float xs[8 * XPAD];
    __shared__ __half2 h0s[M0 * 64];
    __shared__ __align__(8) float h1s[M1 * 128];

    const int tid = threadIdx.x;
    const int bx = blockIdx.x;
    const int t = bx & 127;
    const int e = bx >> 7;

    const float* __restrict__ xq = x + e * 512;
    for (int i = tid; i < 512; i += 256)
        xs[(i >> 6) * XPAD + (i & 63)] = xq[i];
    __syncthreads();

    run_tree_eighth(t, e, tid, xs, idx0, idx1, idx2, slut, h0s, h1s, out);
}

extern "C" void kernel_launch(void* const* d_in, const int* in_sizes, int n_in,
                              void* d_out, int out_size, void* d_ws, size_t ws_size,
                              hipStream_t stream) {
    const float* x    = (const float*)d_in[0];
    const int*   idx0 = (const int*)  d_in[1];
    const float* lut0 = (const float*)d_in[2];
    const int*   idx1 = (const int*)  d_in[3];
    const float* lut1 = (const float*)d_in[4];
    const int*   idx2 = (const int*)  d_in[5];
    const float* lut2 = (const float*)d_in[6];
    float* out = (float*)d_out;
    float* slut = (float*)d_ws;   // 1.41 MB

    void* args[] = {(void*)&x, (void*)&idx0, (void*)&lut0, (void*)&idx1,
                    (void*)&lut1, (void*)&idx2, (void*)&lut2,
                    (void*)&slut, (void*)&out};
    hipError_t err = hipLaunchCooperativeKernel(
        reinterpret_cast<void*>(coop_kernel), dim3(8 * T_TREES), dim3(256),
        args, 0, stream);
    if (err != hipSuccess) {
        // proven two-dispatch path (R16)
        sig_kernel<<<SLUT_ELEMS / 4 / 256, 256, 0, stream>>>(lut0, lut1, lut2, slut);
        fused_kernel<<<dim3(8 * T_TREES), 256, 0, stream>>>(
            x, idx0, idx1, idx2, slut, out);
    }
}

// Round 18
// 23.787 us; speedup vs baseline: 4.3462x; 4.3462x over previous
//
#include <hip/hip_runtime.h>
#include <hip/hip_fp16.h>

// Problem constants (fixed by setup_inputs):
//   x: (64,1,8,8) f32; KH=KW=5 -> oh=ow=4; rows n = b*16 + s, N = 1024
//   feat[n, i*5+j] = x[b*64 + (oy+i)*8 + (ox+j)], s = oy*4+ox
//   idx0:(128,36,6) in [0,25), lut0:(128,36,64)
//   idx1:(128, 6,6) in [0,36), lut1:(128, 6,64)
//   idx2:(128, 1,6) in [0, 6), lut2:(128, 1,64)
//   out[b,t,oy,ox] = b*2048 + t*16 + s
#define T_TREES 128
#define M0 36
#define M1 6
#define NNODES 43
#define TREE_SL (NNODES * 64)   // 2752 floats = 11 KB per tree
#define XPAD 67   // odd LDS image stride -> gather banks sweep residues (~2-way, free)

typedef float v2f __attribute__((ext_vector_type(2)));

__device__ __forceinline__ float sigmoidf(float v) {
    return 1.f / (1.f + __expf(-v));
}

// Pair-weight, FMA-lean: {(1-a)(1-b),(1-a)b,a(1-b),ab} per 2-row lane.
__device__ __forceinline__ void pair_w(v2f a, v2f b, v2f w[4]) {
    v2f ab = a * b;
    w[3] = ab;
    w[2] = a - ab;
    w[1] = b - ab;
    w[0] = (1.f - a) - w[1];
}

// Trilinear contraction over a row-pair; P compile-time indexed (regs).
__device__ __forceinline__ v2f lut_node_v2(const float* __restrict__ P,
                                           v2f a, v2f b, v2f c,
                                           v2f d, v2f e, v2f f) {
    v2f wa[4], wb[4], wc[4];
    pair_w(a, b, wa);
    pair_w(c, d, wb);
    pair_w(e, f, wc);
    v2f acc = {0.f, 0.f};
#pragma unroll
    for (int p = 0; p < 4; ++p) {
        v2f tp = {0.f, 0.f};
#pragma unroll
        for (int q = 0; q < 4; ++q) {
            const float* Pq = P + p * 16 + q * 4;
            v2f tq = Pq[0] * wc[0] + Pq[1] * wc[1] + Pq[2] * wc[2] + Pq[3] * wc[3];
            tp += tq * wb[q];
        }
        acc += tp * wa[p];
    }
    return acc;
}

// batch-hoist one node's 64 sigmoided LUT values from GLOBAL scratch at a
// uniform address: 16 broadcast dwordx4 (one 16B line each, L1-hot after the
// first node) on the otherwise-idle VMEM pipe -- NOT the per-CU LDS pipe,
// which R15's arithmetic showed was the binding resource (~7us of broadcast
// ds_read_b128). One batched wait, then a load-free FMA stream (R4 mechanism).
__device__ __forceinline__ void hoist_P(const float* __restrict__ src, float P[64]) {
#pragma unroll
    for (int i = 0; i < 16; ++i) {
        float4 v = reinterpret_cast<const float4*>(src)[i];
        P[4 * i] = v.x; P[4 * i + 1] = v.y; P[4 * i + 2] = v.z; P[4 * i + 3] = v.w;
    }
}

// ===== single-dispatch fused kernel: block = (tree t, 256-row quarter) =====
// Phase 0: block computes its tree's 43x64 sigmoids into a PRIVATE global
// scratch slice (11 KB; write-through to L2) and stages the quarter's x.
// threadfence_block + barrier, then layers 0-2 with P hoisted from that slice.
// LDS = 28.9 KB (xs + f16 h0 + h1) and carries only gathers; same proven
// mechanisms as R15 otherwise (2 pair-iter amortization, v2f math, odd XPAD,
// t-fast grid for XCD locality). No min-waves clamp (R5 spill lesson).
__global__ __launch_bounds__(256) void fused_kernel(
    const float* __restrict__ x,
    const int* __restrict__ idx0, const float* __restrict__ lut0,
    const int* __restrict__ idx1, const float* __restrict__ lut1,
    const int* __restrict__ idx2, const float* __restrict__ lut2,
    float* __restrict__ ws_slut, float* __restrict__ out) {
    __shared__ float xs[16 * XPAD];               //  4288 B: quarter's 16 images
    __shared__ __half2 h0s[M0 * 128];             // 18432 B (pair-packed f16)
    __shared__ __align__(8) float h1s[M1 * 256];  //  6144 B  => 28864 B total

    const int tid = threadIdx.x;
    const int bx = blockIdx.x;            // bx = q*128 + t (t fast -> XCD locality)
    const int t = bx & 127;
    const int q = bx >> 7;                // row quarter [0,4)

    float* __restrict__ slb = ws_slut + (size_t)bx * TREE_SL;  // private slice

    // ---- phase 0: stage x quarter + sigmoid this tree's LUTs to global ----
    const float* __restrict__ xq = x + q * 1024;
    for (int i = tid; i < 1024; i += 256)
        xs[(i >> 6) * XPAD + (i & 63)] = xq[i];
    for (int i = tid; i < TREE_SL; i += 256) {
        float v;
        if (i < M0 * 64)              v = lut0[t * (M0 * 64) + i];
        else if (i < (M0 + M1) * 64)  v = lut1[t * (M1 * 64) + (i - M0 * 64)];
        else                          v = lut2[t * 64 + (i - (M0 + M1) * 64)];
        slb[i] = sigmoidf(v);
    }
    __threadfence_block();   // drain stores (vmcnt) before other waves read
    __syncthreads();

    const int w = __builtin_amdgcn_readfirstlane(tid >> 6);  // uniform wave id
    const int ln = tid & 63;

    // ---- layer 0: wave w -> nodes 9w..9w+8; 2 pair-iters each ----
#pragma unroll 1
    for (int k = 0; k < 9; ++k) {
        const int m = w * 9 + k;
        float P[64];
        hoist_P(slb + m * 64, P);
        const int* id = idx0 + (t * M0 + m) * 6;   // wave-uniform -> scalar
        int di[6];
#pragma unroll
        for (int j = 0; j < 6; ++j) {
            int kk = id[j];
            int ii = (kk * 13) >> 6;      // kk/5 for kk in [0,25)
            di[j] = kk - 5 * ii + ii * 8; // i*8 + j window offset
        }
#pragma unroll
        for (int u = 0; u < 2; ++u) {
            int p = u * 64 + ln;          // local pair: rows 2p,2p+1
            int b = p >> 3;               // local image [0,16)
            int s = (p & 7) * 2;          // even position
            int xb = b * XPAD + (s >> 2) * 8 + (s & 3);
            v2f g[6];
#pragma unroll
            for (int j = 0; j < 6; ++j) {
                int a0 = xb + di[j];
                g[j].x = xs[a0];          // fuses -> ds_read2_b32
                g[j].y = xs[a0 + 1];
            }
            v2f r = lut_node_v2(P, g[0], g[1], g[2], g[3], g[4], g[5]);
            h0s[m * 128 + p] = __floats2half2_rn(r.x, r.y);
        }
    }
    __syncthreads();

    // ---- layer 1: wave0: nodes 0,4; wave1: 1,5; wave2: 2; wave3: 3 ----
#pragma unroll 1
    for (int m1 = w; m1 < M1; m1 += 4) {
        float P[64];
        hoist_P(slb + (M0 + m1) * 64, P);
        const int* id = idx1 + (t * M1 + m1) * 6;
#pragma unroll
        for (int u = 0; u < 2; ++u) {
            int p = u * 64 + ln;
            v2f g[6];
#pragma unroll
            for (int j = 0; j < 6; ++j) {
                float2 f = __half22float2(h0s[id[j] * 128 + p]);
                g[j].x = f.x; g[j].y = f.y;
            }
            v2f r = lut_node_v2(P, g[0], g[1], g[2], g[3], g[4], g[5]);
            *reinterpret_cast<v2f*>(h1s + m1 * 256 + 2 * p) = r;
        }
    }
    __syncthreads();

    // ---- layer 2: first 2 waves, one pair per thread ----
    if (tid < 128) {
        float P[64];
        hoist_P(slb + (M0 + M1) * 64, P);
        const int* id = idx2 + t * 6;
        int rl = 2 * tid;                 // local even row
        v2f g[6];
#pragma unroll
        for (int j = 0; j < 6; ++j)
            g[j] = *reinterpret_cast<const v2f*>(h1s + id[j] * 256 + rl);
        v2f o = lut_node_v2(P, g[0], g[1], g[2], g[3], g[4], g[5]);
        int row = q * 256 + rl;
        int b = row >> 4, s = row & 15;
        *reinterpret_cast<v2f*>(out + b * (T_TREES * 16) + t * 16 + s) = o;
    }
}

// ===== fallback (ws too small): R15's proven 22.56us self-contained kernel =====
__global__ __launch_bounds__(256, 2) void fused_fb_kernel(
    const float* __restrict__ x,
    const int* __restrict__ idx0, const float* __restrict__ lut0,
    const int* __restrict__ idx1, const float* __restrict__ lut1,
    const int* __restrict__ idx2, const float* __restrict__ lut2,
    float* __restrict__ out) {
    __shared__ float xs[16 * XPAD];
    __shared__ __align__(16) float Ps[NNODES * 64];
    __shared__ __half2 h0s[M0 * 128];
    __shared__ __align__(8) float h1s[M1 * 256];

    const int tid = threadIdx.x;
    const int bx = blockIdx.x;
    const int t = bx & 127;
    const int q = bx >> 7;

    const float* __restrict__ xq = x + q * 1024;
    for (int i = tid; i < 1024; i += 256)
        xs[(i >> 6) * XPAD + (i & 63)] = xq[i];
    for (int i = tid; i < NNODES * 64; i += 256) {
        float v;
        if (i < M0 * 64)              v = lut0[t * (M0 * 64) + i];
        else if (i < (M0 + M1) * 64)  v = lut1[t * (M1 * 64) + (i - M0 * 64)];
        else                          v = lut2[t * 64 + (i - (M0 + M1) * 64)];
        Ps[i] = sigmoidf(v);
    }
    __syncthreads();

    const int w = tid >> 6, ln = tid & 63;
#pragma unroll 1
    for (int k = 0; k < 9; ++k) {
        const int m = w * 9 + k;
        float P[64];
        hoist_P(Ps + m * 64, P);
        const int* id = idx0 + (t * M0 + m) * 6;
        int di[6];
#pragma unroll
        for (int j = 0; j < 6; ++j) {
            int kk = id[j];
            int ii = (kk * 13) >> 6;
            di[j] = kk - 5 * ii + ii * 8;
        }
#pragma unroll
        for (int u = 0; u < 2; ++u) {
            int p = u * 64 + ln;
            int b = p >> 3;
            int s = (p & 7) * 2;
            int xb = b * XPAD + (s >> 2) * 8 + (s & 3);
            v2f g[6];
#pragma unroll
            for (int j = 0; j < 6; ++j) {
                int a0 = xb + di[j];
                g[j].x = xs[a0];
                g[j].y = xs[a0 + 1];
            }
            v2f r = lut_node_v2(P, g[0], g[1], g[2], g[3], g[4], g[5]);
            h0s[m * 128 + p] = __floats2half2_rn(r.x, r.y);
        }
    }
    __syncthreads();
#pragma unroll 1
    for (int m1 = w; m1 < M1; m1 += 4) {
        float P[64];
        hoist_P(Ps + (M0 + m1) * 64, P);
        const int* id = idx1 + (t * M1 + m1) * 6;
#pragma unroll
        for (int u = 0; u < 2; ++u) {
            int p = u * 64 + ln;
            v2f g[6];
#pragma unroll
            for (int j = 0; j < 6; ++j) {
                float2 f = __half22float2(h0s[id[j] * 128 + p]);
                g[j].x = f.x; g[j].y = f.y;
            }
            v2f r = lut_node_v2(P, g[0], g[1], g[2], g[3], g[4], g[5]);
            *reinterpret_cast<v2f*>(h1s + m1 * 256 + 2 * p) = r;
        }
    }
    __syncthreads();
    if (tid < 128) {
        float P[64];
        hoist_P(Ps + (M0 + M1) * 64, P);
        const int* id = idx2 + t * 6;
        int rl = 2 * tid;
        v2f g[6];
#pragma unroll
        for (int j = 0; j < 6; ++j)
            g[j] = *reinterpret_cast<const v2f*>(h1s + id[j] * 256 + rl);
        v2f o = lut_node_v2(P, g[0], g[1], g[2], g[3], g[4], g[5]);
        int row = q * 256 + rl;
        int b = row >> 4, s = row & 15;
        *reinterpret_cast<v2f*>(out + b * (T_TREES * 16) + t * 16 + s) = o;
    }
}

extern "C" void kernel_launch(void* const* d_in, const int* in_sizes, int n_in,
                              void* d_out, int out_size, void* d_ws, size_t ws_size,
                              hipStream_t stream) {
    const float* x    = (const float*)d_in[0];
    const int*   idx0 = (const int*)  d_in[1];
    const float* lut0 = (const float*)d_in[2];
    const int*   idx1 = (const int*)  d_in[3];
    const float* lut1 = (const float*)d_in[4];
    const int*   idx2 = (const int*)  d_in[5];
    const float* lut2 = (const float*)d_in[6];
    float* out = (float*)d_out;

    const size_t need = (size_t)512 * TREE_SL * sizeof(float);   // 5.6 MB
    if (ws_size >= need) {
        fused_kernel<<<dim3(4 * T_TREES), 256, 0, stream>>>(
            x, idx0, lut0, idx1, lut1, idx2, lut2, (float*)d_ws, out);
    } else {
        fused_fb_kernel<<<dim3(4 * T_TREES), 256, 0, stream>>>(
            x, idx0, lut0, idx1, lut1, idx2, lut2, out);
    }
}

// Round 19
// 20.169 us; speedup vs baseline: 5.1258x; 1.1794x over previous
//
#include <hip/hip_runtime.h>
#include <hip/hip_fp16.h>

// Problem constants (fixed by setup_inputs):
//   x: (64,1,8,8) f32; KH=KW=5 -> oh=ow=4; rows n = b*16 + s, N = 1024
//   feat[n, i*5+j] = x[b*64 + (oy+i)*8 + (ox+j)], s = oy*4+ox
//   idx0:(128,36,6) in [0,25), lut0:(128,36,64)
//   idx1:(128, 6,6) in [0,36), lut1:(128, 6,64)
//   idx2:(128, 1,6) in [0, 6), lut2:(128, 1,64)
//   out[b,t,oy,ox] = b*2048 + t*16 + s
#define T_TREES 128
#define M0 36
#define M1 6
#define NNODES 43
#define TREE_SL (NNODES * 64)   // 2752
#define XPAD 67   // odd LDS image stride -> gather banks sweep residues (~2-way, free)

typedef float v2f __attribute__((ext_vector_type(2)));

__device__ __forceinline__ float sigmoidf(float v) {
    return 1.f / (1.f + __expf(-v));
}

// Pair-weight, FMA-lean: {(1-a)(1-b),(1-a)b,a(1-b),ab} per 2-row lane.
__device__ __forceinline__ void pair_w(v2f a, v2f b, v2f w[4]) {
    v2f ab = a * b;
    w[3] = ab;
    w[2] = a - ab;
    w[1] = b - ab;
    w[0] = (1.f - a) - w[1];
}

// Trilinear contraction over a row-pair; P compile-time indexed (regs).
__device__ __forceinline__ v2f lut_node_v2(const float* __restrict__ P,
                                           v2f a, v2f b, v2f c,
                                           v2f d, v2f e, v2f f) {
    v2f wa[4], wb[4], wc[4];
    pair_w(a, b, wa);
    pair_w(c, d, wb);
    pair_w(e, f, wc);
    v2f acc = {0.f, 0.f};
#pragma unroll
    for (int p = 0; p < 4; ++p) {
        v2f tp = {0.f, 0.f};
#pragma unroll
        for (int q = 0; q < 4; ++q) {
            const float* Pq = P + p * 16 + q * 4;
            v2f tq = Pq[0] * wc[0] + Pq[1] * wc[1] + Pq[2] * wc[2] + Pq[3] * wc[3];
            tp += tq * wb[q];
        }
        acc += tp * wa[p];
    }
    return acc;
}

// batch-hoist one node's 64 sigmoided LUT values from f16 LDS: 8 broadcast
// ds_read_b128 (half the LDS-pipe bytes of the f32 hoist) + 64 cheap VALU
// converts. One batched wait, then a load-free FMA stream (R4 mechanism).
__device__ __forceinline__ void hoist_P16(const __half2* __restrict__ src, float P[64]) {
#pragma unroll
    for (int i = 0; i < 8; ++i) {
        float4 v = reinterpret_cast<const float4*>(src)[i];   // 8 halfs
        float2 f0 = __half22float2(__builtin_bit_cast(__half2, v.x));
        float2 f1 = __half22float2(__builtin_bit_cast(__half2, v.y));
        float2 f2 = __half22float2(__builtin_bit_cast(__half2, v.z));
        float2 f3 = __half22float2(__builtin_bit_cast(__half2, v.w));
        P[8 * i + 0] = f0.x; P[8 * i + 1] = f0.y;
        P[8 * i + 2] = f1.x; P[8 * i + 3] = f1.y;
        P[8 * i + 4] = f2.x; P[8 * i + 5] = f2.y;
        P[8 * i + 6] = f3.x; P[8 * i + 7] = f3.y;
    }
}

// ===== single-dispatch fused kernel: block = (tree t, 512-row HALF) =====
// R15's structure with the two LDS-pipe levers pulled:
//  * half-blocks: 256 blocks (1/CU), so per-CU redundant node-hoists drop
//    86 -> 43 (the binding ~7us term in R15's cost model); per-CU gather and
//    VALU work unchanged; residency still 2 waves/SIMD.
//  * f16 Ps: hoist = 8 ds_read_b128 instead of 16; unpack on the VALU pipe
//    (which has headroom). Precision: P err ~2.4e-4 on (0,1), f16-h0 already
//    passes at 3.9e-3 vs 1.19e-2 threshold.
// 8 waves: layer-0 nodes dealt m = w, w+8, ... (waves 0-3 get 5, 4-7 get 4);
// no workspace, no prepass dispatch, no min-waves clamp (R5 spill lesson).
__global__ __launch_bounds__(512) void fused_kernel(
    const float* __restrict__ x,
    const int* __restrict__ idx0, const float* __restrict__ lut0,
    const int* __restrict__ idx1, const float* __restrict__ lut1,
    const int* __restrict__ idx2, const float* __restrict__ lut2,
    float* __restrict__ out) {
    __shared__ float xs[32 * XPAD];               //  8576 B: half's 32 images
    __shared__ __align__(16) __half2 Psh[NNODES * 32];  // 5504 B sigmoided LUTs (f16)
    __shared__ __half2 h0s[M0 * 256];             // 36864 B (pair-packed f16)
    __shared__ __align__(8) float h1s[M1 * 512];  // 12288 B  => 63232 B total

    const int tid = threadIdx.x;
    const int bx = blockIdx.x;            // bx = h*128 + t (t fast -> XCD locality)
    const int t = bx & 127;
    const int h = bx >> 7;                // row half [0,2)

    // ---- prologue: stage 32 images + sigmoid all 43 node LUTs to f16 LDS ----
    const float* __restrict__ xq = x + h * 2048;
    for (int i = tid; i < 2048; i += 512)
        xs[(i >> 6) * XPAD + (i & 63)] = xq[i];
    for (int i = tid; i < TREE_SL / 2; i += 512) {   // 1376 half2 elements
        int e = 2 * i;                    // even element; pair stays in one lut
        float2 v;
        if (e < M0 * 64)
            v = *reinterpret_cast<const float2*>(lut0 + t * (M0 * 64) + e);
        else if (e < (M0 + M1) * 64)
            v = *reinterpret_cast<const float2*>(lut1 + t * (M1 * 64) + (e - M0 * 64));
        else
            v = *reinterpret_cast<const float2*>(lut2 + t * 64 + (e - (M0 + M1) * 64));
        Psh[i] = __floats2half2_rn(sigmoidf(v.x), sigmoidf(v.y));
    }
    __syncthreads();

    const int w = __builtin_amdgcn_readfirstlane(tid >> 6);  // wave id 0..7
    const int ln = tid & 63;

    // ---- layer 0: wave w -> nodes w, w+8, ...; 4 pair-iters each ----
#pragma unroll 1
    for (int m = w; m < M0; m += 8) {
        float P[64];
        hoist_P16(Psh + m * 32, P);
        const int* id = idx0 + (t * M0 + m) * 6;   // wave-uniform -> scalar
        int di[6];
#pragma unroll
        for (int j = 0; j < 6; ++j) {
            int kk = id[j];
            int ii = (kk * 13) >> 6;      // kk/5 for kk in [0,25)
            di[j] = kk - 5 * ii + ii * 8; // i*8 + j window offset
        }
#pragma unroll
        for (int u = 0; u < 4; ++u) {
            int p = u * 64 + ln;          // local pair [0,256): rows 2p,2p+1
            int b = p >> 3;               // local image [0,32)
            int s = (p & 7) * 2;          // even position
            int xb = b * XPAD + (s >> 2) * 8 + (s & 3);
            v2f g[6];
#pragma unroll
            for (int j = 0; j < 6; ++j) {
                int a0 = xb + di[j];
                g[j].x = xs[a0];          // fuses -> ds_read2_b32
                g[j].y = xs[a0 + 1];
            }
            v2f r = lut_node_v2(P, g[0], g[1], g[2], g[3], g[4], g[5]);
            h0s[m * 256 + p] = __floats2half2_rn(r.x, r.y);
        }
    }
    __syncthreads();

    // ---- layer 1: waves 0-5, one node each; 4 pair-iters ----
#pragma unroll 1
    for (int m1 = w; m1 < M1; m1 += 8) {
        float P[64];
        hoist_P16(Psh + (M0 + m1) * 32, P);
        const int* id = idx1 + (t * M1 + m1) * 6;
#pragma unroll
        for (int u = 0; u < 4; ++u) {
            int p = u * 64 + ln;
            v2f g[6];
#pragma unroll
            for (int j = 0; j < 6; ++j) {
                float2 f = __half22float2(h0s[id[j] * 256 + p]);
                g[j].x = f.x; g[j].y = f.y;
            }
            v2f r = lut_node_v2(P, g[0], g[1], g[2], g[3], g[4], g[5]);
            *reinterpret_cast<v2f*>(h1s + m1 * 512 + 2 * p) = r;
        }
    }
    __syncthreads();

    // ---- layer 2: first 4 waves, one pair per thread (256 pairs) ----
    if (tid < 256) {
        float P[64];
        hoist_P16(Psh + (M0 + M1) * 32, P);
        const int* id = idx2 + t * 6;
        int rl = 2 * tid;                 // local even row [0,512)
        v2f g[6];
#pragma unroll
        for (int j = 0; j < 6; ++j)
            g[j] = *reinterpret_cast<const v2f*>(h1s + id[j] * 512 + rl);
        v2f o = lut_node_v2(P, g[0], g[1], g[2], g[3], g[4], g[5]);
        int row = h * 512 + rl;
        int b = row >> 4, s = row & 15;
        *reinterpret_cast<v2f*>(out + b * (T_TREES * 16) + t * 16 + s) = o;
    }
}

extern "C" void kernel_launch(void* const* d_in, const int* in_sizes, int n_in,
                              void* d_out, int out_size, void* d_ws, size_t ws_size,
                              hipStream_t stream) {
    const float* x    = (const float*)d_in[0];
    const int*   idx0 = (const int*)  d_in[1];
    const float* lut0 = (const float*)d_in[2];
    const int*   idx1 = (const int*)  d_in[3];
    const float* lut1 = (const float*)d_in[4];
    const int*   idx2 = (const int*)  d_in[5];
    const float* lut2 = (const float*)d_in[6];
    float* out = (float*)d_out;

    fused_kernel<<<dim3(2 * T_TREES), 512, 0, stream>>>(
        x, idx0, lut0, idx1, lut1, idx2, lut2, out);   // 256 blocks = 1/CU
}